// Round 5
// baseline (198.370 us; speedup 1.0000x reference)
//
#include <hip/hip_runtime.h>
#include <math.h>

// Problem constants (B=16, H=512, W=512, fp32 in/out)
#define BB 16
#define HH 512
#define WW 512
#define NPIX (BB*HH*WW)   // 4194304
#define NROWS (BB*HH)     // 8192
#define NWORDS 16         // 512 rows / 32 bits
#define PADK 512          // pad each side of the horizontal LDS row

// ---------------------------------------------------------------------------
// Kernel A: build column bitmasks + per-column nearest-set-bit tables.
// 256 blocks x 512 threads: block = (b, 32-col tile), thread owns one
// (word k, col c) -> 32 coalesced strided loads. Then wave 0 (lanes 0-31)
// does the suffix scan (un) and wave 1 the prefix scan (dn):
//   un[b][k][w] = abs pos of first set bit >= 32k   (slot 16 = +16000)
//   dn[b][k+1][w] = abs pos of last set bit <= 32k+31 (slot 0 = -16000)
// Also zeroes the completion counter used by the fused finalize.
// ---------------------------------------------------------------------------
__global__ __launch_bounds__(512) void build_kernel(
    const float* __restrict__ tg, unsigned int* __restrict__ mask,
    short* __restrict__ un_s, short* __restrict__ dn_s,
    unsigned int* __restrict__ counter) {
  __shared__ unsigned int smask[NWORDS][32];
  int wt = blockIdx.x & 15;          // 16 col-tiles of 32
  int b  = blockIdx.x >> 4;
  int c  = threadIdx.x & 31;
  int k  = threadIdx.x >> 5;         // 0..15
  int w  = (wt << 5) + c;
  if (blockIdx.x == 0 && threadIdx.x == 0) *counter = 0;
  const float* p = tg + ((size_t)(b * HH + (k << 5))) * WW + w;
  unsigned int word = 0;
  #pragma unroll
  for (int r = 0; r < 32; ++r)
    word |= (p[(size_t)r * WW] > 0.f ? 1u : 0u) << r;
  smask[k][c] = word;
  mask[(b * NWORDS + k) * WW + w] = word;
  __syncthreads();
  int t = threadIdx.x;
  if (t < 32) {                      // wave 0: suffix scan (first set >= 32k)
    int wcol = (wt << 5) + t;
    int cur = 16000;
    un_s[(b * 17 + 16) * WW + wcol] = (short)cur;
    #pragma unroll
    for (int k2 = NWORDS - 1; k2 >= 0; --k2) {
      unsigned int m = smask[k2][t];
      if (m) cur = (k2 << 5) + (int)__builtin_ctz(m);
      un_s[(b * 17 + k2) * WW + wcol] = (short)cur;
    }
  } else if (t >= 64 && t < 96) {    // wave 1: prefix scan (last set <= 32k+31)
    int tt = t - 64;
    int wcol = (wt << 5) + tt;
    int cur = -16000;
    dn_s[(b * 17 + 0) * WW + wcol] = (short)cur;
    #pragma unroll
    for (int k2 = 0; k2 < NWORDS; ++k2) {
      unsigned int m = smask[k2][tt];
      if (m) cur = (k2 << 5) + 31 - (int)__builtin_clz(m);
      dn_s[(b * 17 + k2 + 1) * WW + wcol] = (short)cur;
    }
  }
}

// ---------------------------------------------------------------------------
// Kernel B: fused vertical EDT (O(1)/px from tables) + horizontal min-plus
// (float2 value-sharing, wave-uniform early exit) + loss + last-block
// finalize. One block per (b, h) row; thread owns adjacent columns 2t, 2t+1.
// All finite distance values are exact small ints in fp32.
// ---------------------------------------------------------------------------
__global__ __launch_bounds__(256) void rows_loss_kernel(
    const float* __restrict__ logits, const unsigned int* __restrict__ mask,
    const short* __restrict__ un_s, const short* __restrict__ dn_s,
    float* __restrict__ partials, unsigned int* __restrict__ counter,
    float* __restrict__ out) {
  __shared__ __align__(16) float sraw[2 * PADK + WW];  // [-512, 1023] around sA
  __shared__ float wsum[4][4];
  __shared__ int lastflag;
  float* sA = sraw + PADK;

  int row = blockIdx.x;             // b*HH + h
  int b = row >> 9, i = row & 511;
  size_t rowbase = (size_t)row * WW;
  int tid = threadIdx.x;
  int w0 = tid << 1;

  // pads (never allowed to win the min)
  *(float2*)&sraw[w0] = make_float2(3e12f, 3e12f);
  *(float2*)&sraw[1024 + w0] = make_float2(3e12f, 3e12f);

  int k0 = i >> 5, pos = i & 31;    // block-uniform
  unsigned int pmask_lo = (1u << pos) - 1u;
  unsigned int pmask_le = pmask_lo | (1u << pos);
  const unsigned int* mrow = mask + (size_t)(b * NWORDS + k0) * WW;
  const short* unrow = un_s + (size_t)(b * 17 + k0 + 1) * WW;
  const short* dnrow = dn_s + (size_t)(b * 17 + k0) * WW;

  uint2 m2 = *(const uint2*)&mrow[w0];          // two adjacent column words
  int un2 = *(const int*)&unrow[w0];            // two shorts
  int dn2 = *(const int*)&dnrow[w0];
  float2 xv = *(const float2*)&logits[rowbase + w0];

  float dvf[2], tval[2];
  #pragma unroll
  for (int j = 0; j < 2; ++j) {
    unsigned int m0 = j ? m2.y : m2.x;
    int un_next = (int)(short)(j ? (un2 >> 16) : (un2 & 0xffff));
    int dn_prev = (int)(short)(j ? (dn2 >> 16) : (dn2 & 0xffff));
    unsigned int upm  = m0 & ~pmask_lo;   // bits >= pos
    unsigned int lowm = m0 & pmask_le;    // bits <= pos
    int up  = upm  ? ((k0 << 5) + (int)__builtin_ctz(upm))       : un_next;
    int dnv = lowm ? ((k0 << 5) + 31 - (int)__builtin_clz(lowm)) : dn_prev;
    int bestv = min(up - i, i - dnv);
    tval[j] = (up == i) ? 1.f : 0.f;      // bit i set iff nearest-up is i
    dvf[j] = (bestv > 511) ? 1e12f : (float)(bestv * bestv);
  }
  *(float2*)&sA[w0] = make_float2(dvf[0], dvf[1]);
  __syncthreads();

  // Horizontal min-plus: chunked outward scan, float2 reads shared by both px.
  float best0 = dvf[0], best1 = dvf[1];
  for (int o0 = 1; o0 < WW; o0 += 8) {    // o0 odd: 1, 9, 17, ...
    float foo0 = (float)(o0 * o0);
    if (__all(foo0 >= fmaxf(best0, best1))) break;
    float2 Lv[5], Rv[5];
    int lb = w0 - o0 - 7;   // even base; covers indices lb .. lb+9
    int rb = w0 + o0 - 1;   // even base; covers rb .. rb+9
    #pragma unroll
    for (int m = 0; m < 5; ++m) {
      Lv[m] = *(const float2*)&sA[lb + 2 * m];
      Rv[m] = *(const float2*)&sA[rb + 2 * m];
    }
    #pragma unroll
    for (int u = 0; u < 8; ++u) {
      float oo = (float)((o0 + u) * (o0 + u));
      // px0 left idx = lb + (7-u); px1 left = lb + (8-u)
      // px0 right idx = rb + (u+1); px1 right = rb + (u+2)
      float l0 = ((7 - u) & 1) ? Lv[(7 - u) >> 1].y : Lv[(7 - u) >> 1].x;
      float l1 = ((8 - u) & 1) ? Lv[(8 - u) >> 1].y : Lv[(8 - u) >> 1].x;
      float r0 = ((u + 1) & 1) ? Rv[(u + 1) >> 1].y : Rv[(u + 1) >> 1].x;
      float r1 = ((u + 2) & 1) ? Rv[(u + 2) >> 1].y : Rv[(u + 2) >> 1].x;
      best0 = fminf(best0, fminf(l0, r0) + oo);
      best1 = fminf(best1, fminf(l1, r1) + oo);
    }
  }

  // Loss terms
  float acc_p = 0.f, acc_t = 0.f, acc_pt = 0.f, acc_pen = 0.f;
  #pragma unroll
  for (int j = 0; j < 2; ++j) {
    float x = j ? xv.y : xv.x;
    float best = j ? best1 : best0;
    float e = __expf(-x);
    float p = __builtin_amdgcn_rcpf(1.f + e);     // sigmoid
    float t = tval[j];
    // empty sample => best ~ 1e12 => reference forces weight 0 (has_fg)
    float wgt = (best > 1e9f)
                    ? 0.f
                    : (1.f - __expf(-__builtin_amdgcn_sqrtf(best) * 0.02f));
    acc_p  += p;
    acc_t  += t;
    acc_pt += p * t;
    acc_pen += wgt * p * (1.f - t);
  }

  // wave(64) shuffle reduce, then across the 4 waves via LDS
  #pragma unroll
  for (int off = 32; off; off >>= 1) {
    acc_p  += __shfl_down(acc_p,  off);
    acc_t  += __shfl_down(acc_t,  off);
    acc_pt += __shfl_down(acc_pt, off);
    acc_pen += __shfl_down(acc_pen, off);
  }
  int wave = tid >> 6, lane = tid & 63;
  if (lane == 0) {
    wsum[wave][0] = acc_p; wsum[wave][1] = acc_t;
    wsum[wave][2] = acc_pt; wsum[wave][3] = acc_pen;
  }
  __syncthreads();
  if (tid == 0) {
    float r0 = 0.f, r1 = 0.f, r2 = 0.f, r3 = 0.f;
    #pragma unroll
    for (int wv = 0; wv < 4; ++wv) {
      r0 += wsum[wv][0]; r1 += wsum[wv][1];
      r2 += wsum[wv][2]; r3 += wsum[wv][3];
    }
    partials[0 * NROWS + row] = r0;
    partials[1 * NROWS + row] = r1;
    partials[2 * NROWS + row] = r2;
    partials[3 * NROWS + row] = r3;
    __threadfence();                         // release partials
    unsigned int prev = atomicAdd(counter, 1u);
    lastflag = (prev == NROWS - 1) ? 1 : 0;
  }
  __syncthreads();

  // Last finished block reduces all partials and writes the scalar loss.
  if (lastflag) {
    __threadfence();                         // acquire other blocks' partials
    float a0 = 0.f, a1 = 0.f, a2 = 0.f, a3 = 0.f;
    for (int k = tid; k < NROWS; k += 256) {
      a0 += partials[0 * NROWS + k];
      a1 += partials[1 * NROWS + k];
      a2 += partials[2 * NROWS + k];
      a3 += partials[3 * NROWS + k];
    }
    #pragma unroll
    for (int off = 32; off; off >>= 1) {
      a0 += __shfl_down(a0, off);
      a1 += __shfl_down(a1, off);
      a2 += __shfl_down(a2, off);
      a3 += __shfl_down(a3, off);
    }
    if (lane == 0) {
      wsum[wave][0] = a0; wsum[wave][1] = a1;
      wsum[wave][2] = a2; wsum[wave][3] = a3;
    }
    __syncthreads();
    if (tid == 0) {
      float sp = 0.f, st = 0.f, inter = 0.f, pen = 0.f;
      #pragma unroll
      for (int wv = 0; wv < 4; ++wv) {
        sp += wsum[wv][0]; st += wsum[wv][1];
        inter += wsum[wv][2]; pen += wsum[wv][3];
      }
      float uni = sp + st - inter;
      float iou_loss = 1.f - (inter + 1e-6f) / (uni + 1e-6f);
      float penalty = pen / (float)NPIX;
      out[0] = iou_loss + 0.5f * penalty;
    }
  }
}

extern "C" void kernel_launch(void* const* d_in, const int* in_sizes, int n_in,
                              void* d_out, int out_size, void* d_ws, size_t ws_size,
                              hipStream_t stream) {
  const float* logits = (const float*)d_in[0];
  const float* tg     = (const float*)d_in[1];
  char* base = (char*)d_ws;
  unsigned int* mask = (unsigned int*)base;               // 512 KB
  short* un_s = (short*)(base + 524288);                  // 16*17*512 shorts
  short* dn_s = (short*)(base + 802816);
  float* partials = (float*)(base + 1081344);             // 128 KB
  unsigned int* counter = (unsigned int*)(base + 1212416);
  float* out = (float*)d_out;

  hipLaunchKernelGGL(build_kernel, dim3(BB * 16), dim3(512), 0, stream,
                     tg, mask, un_s, dn_s, counter);
  hipLaunchKernelGGL(rows_loss_kernel, dim3(NROWS), dim3(256), 0, stream,
                     logits, mask, un_s, dn_s, partials, counter, out);
}